// Round 11
// baseline (823.149 us; speedup 1.0000x reference)
//
#include <hip/hip_runtime.h>

#define NND 50000
#define NE  800000
#define NET 850000   // NE + NND self-loops
#define NG  2048
#define SCB 196      // scan blocks = ceil(NND/256)
#define MB  1024     // k_mean blocks

typedef __attribute__((ext_vector_type(8))) short short8;    // 8 bf16 (4 VGPRs)
typedef __attribute__((ext_vector_type(4))) float float4v;   // 4 fp32 acc

__device__ __forceinline__ float frelu(float v){ return v > 0.f ? v : 0.f; }

// round-to-nearest-even float -> bf16 bits
__device__ __forceinline__ unsigned short f2bf(float f){
    unsigned int u = __float_as_uint(f);
    u += 0x7FFFu + ((u >> 16) & 1u);
    return (unsigned short)(u >> 16);
}
__device__ __forceinline__ float bf2f(unsigned short s){
    return __uint_as_float(((unsigned int)s) << 16);
}
__device__ __forceinline__ float sel4(float4 v, int m){
    float r = v.x;
    r = (m == 1) ? v.y : r;
    r = (m == 2) ? v.z : r;
    r = (m == 3) ? v.w : r;
    return r;
}

struct MC { float m[8]; };

// ------- mean stage 1 + zero g/cnt: float4 grid-stride, block reduce ------------
__global__ __launch_bounds__(256) void k_mean(const float4* __restrict__ ef4,
                                              float* __restrict__ partial,
                                              float* __restrict__ gz,
                                              int* __restrict__ cntz){
    __shared__ float4 red[256];
    int t = threadIdx.x;
    int i0 = blockIdx.x * 256 + t;
    gz[i0] = 0.f;                            // MB*256 == NG*128 exactly
    if (i0 < NND) cntz[i0] = 0;
    const int S = MB * 256;
    float4 a = make_float4(0.f, 0.f, 0.f, 0.f);
    for (int j = i0; j < NE * 2; j += S){
        float4 v = ef4[j];
        a.x += v.x; a.y += v.y; a.z += v.z; a.w += v.w;
    }
    red[t] = a;
    __syncthreads();
    for (int off = 128; off >= 2; off >>= 1){    // even offsets preserve parity
        if (t < off){
            float4 o = red[t + off];
            float4 m = red[t];
            m.x += o.x; m.y += o.y; m.z += o.z; m.w += o.w;
            red[t] = m;
        }
        __syncthreads();
    }
    if (t < 8){
        float v = (t < 4) ? ((const float*)&red[0])[t]
                          : ((const float*)&red[1])[t - 4];
        partial[blockIdx.x * 8 + t] = v;
    }
}

// -------- prep: reduce partials -> mean; M[3][8][4]; self-loop consts sc[3][4] --
__global__ void k_prep(const float* __restrict__ partial,
                       const float* __restrict__ We1, const float* __restrict__ ae1,
                       const float* __restrict__ We2, const float* __restrict__ ae2,
                       const float* __restrict__ We3, const float* __restrict__ ae3,
                       float* __restrict__ M, float* __restrict__ sc){
    __shared__ float me[8];
    __shared__ float pm[16][8];
    __shared__ float Ms[96];
    int t = threadIdx.x;
    {
        int ch = t & 7, seg = t >> 3;
        float s = 0.f;
        for (int j = seg; j < MB; j += 16) s += partial[j * 8 + ch];
        pm[seg][ch] = s;
    }
    __syncthreads();
    if (t < 8){
        float s = 0.f;
        for (int i = 0; i < 16; i++) s += pm[i][t];
        me[t] = s * (1.0f / NE);
    }
    if (t < 96){
        int l = t >> 5, f = (t >> 2) & 7, h = t & 3;
        const float* We = (l == 0) ? We1 : ((l == 1) ? We2 : We3);
        const float* ae = (l == 0) ? ae1 : ((l == 1) ? ae2 : ae3);
        float s = 0.f;
        for (int c = 0; c < 32; c++) s += We[f * 128 + h * 32 + c] * ae[h * 32 + c];
        M[t] = s; Ms[t] = s;
    }
    __syncthreads();
    if (t < 12){
        int l = t >> 2, h = t & 3;
        float s = 0.f;
        for (int f = 0; f < 8; f++) s += me[f] * Ms[l * 32 + f * 4 + h];
        sc[t] = s;
    }
}

// ------------- MFMA GEMM: h = x @ W (bf16), fused als/ald epilogue --------------
// 64 rows x 128 cols per 256-thread block. BFIN: x is packed bf16 rows.
template<int FIN, int FINR, int BFIN>
__global__ __launch_bounds__(256) void k_gemm(
        const void* __restrict__ xv, const float* __restrict__ W,
        const float* __restrict__ asrc, const float* __restrict__ adst,
        unsigned short* __restrict__ h, float* __restrict__ als,
        float* __restrict__ ald){
    constexpr int KS = FIN + 8;
    constexpr int SZ1 = 64 * KS + 128 * KS;
    constexpr int SZ2 = 64 * 136;
    constexpr int LSZ = SZ1 > SZ2 ? SZ1 : SZ2;
    __shared__ unsigned short lds[LSZ];
    unsigned short* xa = lds;                // [64][KS]
    unsigned short* wb = lds + 64 * KS;      // [128][KS]
    int t = threadIdx.x;
    int r0 = blockIdx.x * 64;

    if (BFIN){
        const unsigned int* xu = (const unsigned int*)xv;
        for (int i = t; i < 64 * (FIN / 2); i += 256){
            int r = i / (FIN / 2), kp = i % (FIN / 2);
            int gr = r0 + r;
            unsigned int pk = (gr < NND) ? xu[gr * (FINR / 2) + kp] : 0u;
            *(unsigned int*)&xa[r * KS + 2 * kp] = pk;
        }
    } else {
        const float* x = (const float*)xv;
        for (int i = t; i < 64 * (FIN / 2); i += 256){
            int r = i / (FIN / 2), kp = i % (FIN / 2);
            int gr = r0 + r, k = 2 * kp;
            float v0 = 0.f, v1 = 0.f;
            if (gr < NND){
                if (k     < FINR) v0 = x[gr * FINR + k];
                if (k + 1 < FINR) v1 = x[gr * FINR + k + 1];
            }
            unsigned int pk = (unsigned int)f2bf(v0) | ((unsigned int)f2bf(v1) << 16);
            *(unsigned int*)&xa[r * KS + k] = pk;
        }
    }
    for (int i = t; i < 128 * (FIN / 2); i += 256){
        int n = i & 127, kp = i >> 7, k = 2 * kp;
        float v0 = (k     < FINR) ? W[k * 128 + n]       : 0.f;
        float v1 = (k + 1 < FINR) ? W[(k + 1) * 128 + n] : 0.f;
        unsigned int pk = (unsigned int)f2bf(v0) | ((unsigned int)f2bf(v1) << 16);
        *(unsigned int*)&wb[n * KS + k] = pk;
    }
    __syncthreads();

    int wv = t >> 6, lane = t & 63;
    int quad = lane >> 4, lrow = lane & 15;
    int arow = wv * 16 + lrow;
    int koff = quad * 8;
    float4v acc[8];
    #pragma unroll
    for (int nt = 0; nt < 8; nt++) acc[nt] = (float4v){0.f, 0.f, 0.f, 0.f};
    #pragma unroll
    for (int ks = 0; ks < FIN / 32; ks++){
        short8 af = *(const short8*)&xa[arow * KS + ks * 32 + koff];
        #pragma unroll
        for (int nt = 0; nt < 8; nt++){
            short8 bf = *(const short8*)&wb[(nt * 16 + lrow) * KS + ks * 32 + koff];
            acc[nt] = __builtin_amdgcn_mfma_f32_16x16x32_bf16(af, bf, acc[nt], 0, 0, 0);
        }
    }
    __syncthreads();
    unsigned short* hb = lds;                // [64][136]
    #pragma unroll
    for (int nt = 0; nt < 8; nt++){
        #pragma unroll
        for (int reg = 0; reg < 4; reg++){
            int lr = wv * 16 + quad * 4 + reg;
            hb[lr * 136 + nt * 16 + lrow] = f2bf(acc[nt][reg]);
        }
    }
    __syncthreads();
    {
        int r = t >> 2, hd = t & 3;
        int gr = r0 + r;
        float sa = 0.f, sd = 0.f;
        const unsigned short* hp = &hb[r * 136 + hd * 32];
        #pragma unroll
        for (int c = 0; c < 32; c++){
            float hv = bf2f(hp[c]);
            sa += hv * asrc[hd * 32 + c];
            sd += hv * adst[hd * 32 + c];
        }
        if (gr < NND){ als[gr * 4 + hd] = sa; ald[gr * 4 + hd] = sd; }
    }
    for (int i = t; i < 64 * 16; i += 256){
        int r = i >> 4, c8 = i & 15;
        int gr = r0 + r;
        if (gr < NND)
            *(int4*)&h[gr * 128 + c8 * 8] = *(const int4*)&hb[r * 136 + c8 * 8];
    }
}

// ------- CSR build: histogram of dst (real edges) + position assignment --------
__global__ void k_hist(const int* __restrict__ ei, int* __restrict__ cnt,
                       int* __restrict__ pose){
    int e = blockIdx.x * 256 + threadIdx.x;
    if (e >= NE) return;
    int d = ei[NE + e];
    pose[e] = atomicAdd(&cnt[d], 1);
}

// ---------------- scan phase 1: per-block sums of (cnt+1) -----------------------
__global__ __launch_bounds__(256) void k_scan1(const int* __restrict__ cnt,
                                               int* __restrict__ bsum){
    __shared__ int red[256];
    int t = threadIdx.x;
    int idx = blockIdx.x * 256 + t;
    red[t] = (idx < NND) ? (cnt[idx] + 1) : 0;
    __syncthreads();
    for (int off = 128; off > 0; off >>= 1){
        if (t < off) red[t] += red[t + off];
        __syncthreads();
    }
    if (t == 0) bsum[blockIdx.x] = red[0];
}

// ---------------- scan phase 2: scan the 196 block sums -------------------------
__global__ __launch_bounds__(256) void k_scan2(const int* __restrict__ bsum,
                                               int* __restrict__ boff,
                                               int* __restrict__ rs){
    __shared__ int ls[256];
    int t = threadIdx.x;
    int v = (t < SCB) ? bsum[t] : 0;
    ls[t] = v;
    __syncthreads();
    for (int off = 1; off < 256; off <<= 1){
        int u = (t >= off) ? ls[t - off] : 0;
        __syncthreads();
        ls[t] += u;
        __syncthreads();
    }
    if (t < SCB) boff[t] = ls[t] - bsum[t];
    if (t == 0)  rs[NND] = ls[255];
}

// ---------------- scan phase 3: per-block exclusive scan + offset ---------------
__global__ __launch_bounds__(256) void k_scan3(const int* __restrict__ cnt,
                                               const int* __restrict__ boff,
                                               int* __restrict__ rs){
    __shared__ int ls[256];
    int t = threadIdx.x;
    int idx = blockIdx.x * 256 + t;
    int v = (idx < NND) ? (cnt[idx] + 1) : 0;
    ls[t] = v;
    __syncthreads();
    for (int off = 1; off < 256; off <<= 1){
        int u = (t >= off) ? ls[t - off] : 0;
        __syncthreads();
        ls[t] += u;
        __syncthreads();
    }
    if (idx < NND) rs[idx] = boff[blockIdx.x] + ls[t] - v;
}

// ---------------- CSR build: scatter (src, edge-id) — NO atomics ----------------
__global__ void k_scatter(const int* __restrict__ ei, const int* __restrict__ rs,
                          const int* __restrict__ pose, int2* __restrict__ se){
    int e = blockIdx.x * 256 + threadIdx.x;
    if (e >= NET) return;
    if (e < NE){
        int s = ei[e], d = ei[NE + e];
        se[rs[d] + 1 + pose[e]] = make_int2(s, e);
    } else {
        int n = e - NE;
        se[rs[n]] = make_int2(n, -1);        // self-loop sentinel
    }
}

// ---- edge attention weight, computed in-gather (all inputs wave-uniform) -------
__device__ __forceinline__ float edge_w(int src, int eid,
        const float4* __restrict__ ef4, const float4* __restrict__ als4,
        const MC& mc, float scv, float aldv, int mh){
    float aeh;
    if (eid >= 0){
        float4 u = ef4[eid * 2], v = ef4[eid * 2 + 1];
        aeh = u.x * mc.m[0] + u.y * mc.m[1] + u.z * mc.m[2] + u.w * mc.m[3]
            + v.x * mc.m[4] + v.y * mc.m[5] + v.z * mc.m[6] + v.w * mc.m[7];
    } else {
        aeh = scv;
    }
    float a = sel4(als4[src], mh) + aldv + aeh;
    a = a > 0.f ? a : 0.2f * a;              // leaky_relu(0.2)
    return __expf(a);
}

// ------- gather (fused weight): bf16 h rows, one wave/node, 8-deep pipeline -----
__global__ __launch_bounds__(256) void k_gather(
        const int2* __restrict__ se, const int* __restrict__ rs,
        const float4* __restrict__ ef4,
        const float4* __restrict__ als4, const float4* __restrict__ ald4,
        const float* __restrict__ Mg, const float* __restrict__ sc4g,
        const unsigned int* __restrict__ HU,    // bf16x2 rows [NND][64]
        const float* __restrict__ b, unsigned int* __restrict__ outU){
    __shared__ float Ms[32];
    __shared__ float Scs[4];
    int t = threadIdx.x;
    if (t < 32) Ms[t] = Mg[t];
    if (t < 4)  Scs[t] = sc4g[t];
    __syncthreads();
    int wid  = t >> 6;
    int lane = t & 63;
    int n = blockIdx.x * 4 + wid;
    int start = rs[n], end = rs[n + 1];
    int cnt = end - start;
    int mh = lane >> 4;
    MC mc;
    #pragma unroll
    for (int f = 0; f < 8; f++) mc.m[f] = Ms[f * 4 + mh];
    float scv  = Scs[mh];
    float aldv = sel4(ald4[n], mh);
    float ax = 0.f, ay = 0.f, accw = 0.f;

    int2 sj[8]; float w[8];
    int k = 0;
    if (cnt >= 8){
        #pragma unroll
        for (int j = 0; j < 8; j++) sj[j] = se[start + j];
        #pragma unroll
        for (int j = 0; j < 8; j++)
            w[j] = edge_w(sj[j].x, sj[j].y, ef4, als4, mc, scv, aldv, mh);
    }
    while (k + 8 <= cnt){
        int cs[8]; float cw[8];
        #pragma unroll
        for (int j = 0; j < 8; j++){ cs[j] = sj[j].x; cw[j] = w[j]; }
        k += 8;
        if (k + 8 <= cnt){
            #pragma unroll
            for (int j = 0; j < 8; j++) sj[j] = se[start + k + j];
            #pragma unroll
            for (int j = 0; j < 8; j++)
                w[j] = edge_w(sj[j].x, sj[j].y, ef4, als4, mc, scv, aldv, mh);
        }
        unsigned int hv[8];
        #pragma unroll
        for (int j = 0; j < 8; j++) hv[j] = HU[cs[j] * 64 + lane];
        #pragma unroll
        for (int j = 0; j < 8; j++){
            float lo = __uint_as_float(hv[j] << 16);
            float hi = __uint_as_float(hv[j] & 0xFFFF0000u);
            ax += cw[j] * lo;
            ay += cw[j] * hi;
            accw += cw[j];
        }
    }
    int rem = cnt - k;
    if (rem > 0){
        int ts[8]; float tw[8];
        #pragma unroll
        for (int j = 0; j < 8; j++){
            bool v = j < rem;
            int i = v ? (start + k + j) : start;     // clamp to self-loop slot
            int2 p = se[i];
            ts[j] = p.x;
            float wj = edge_w(p.x, p.y, ef4, als4, mc, scv, aldv, mh);
            tw[j] = v ? wj : 0.f;
        }
        unsigned int hv[8];
        #pragma unroll
        for (int j = 0; j < 8; j++) hv[j] = HU[ts[j] * 64 + lane];
        #pragma unroll
        for (int j = 0; j < 8; j++){
            float lo = __uint_as_float(hv[j] << 16);
            float hi = __uint_as_float(hv[j] & 0xFFFF0000u);
            ax += tw[j] * lo;
            ay += tw[j] * hi;
            accw += tw[j];
        }
    }
    float inv = 1.f / (accw + 1e-16f);
    int c0 = 2 * lane;
    float ox = frelu(ax * inv + b[c0]);
    float oy = frelu(ay * inv + b[c0 + 1]);
    outU[n * 64 + lane] = (unsigned int)f2bf(ox) | ((unsigned int)f2bf(oy) << 16);
}

// ------- global add pool (bf16 in): run-length compress sorted batch ------------
__global__ __launch_bounds__(128) void k_pool(const unsigned short* __restrict__ y,
                                              const int* __restrict__ batch,
                                              float* __restrict__ g){
    int c = threadIdx.x;
    int n0 = blockIdx.x * 32;
    if (n0 >= NND) return;
    int cur = batch[n0];
    float s = 0.f;
    for (int k = 0; k < 32; k++){
        int n = n0 + k;
        if (n >= NND) break;
        int bg = batch[n];
        if (bg != cur){
            atomicAdd(&g[cur * 128 + c], s);
            s = 0.f; cur = bg;
        }
        s += bf2f(y[n * 128 + c]);
    }
    atomicAdd(&g[cur * 128 + c], s);
}

// ---------------- MLP head: 128->32->32->1 --------------------------------------
__global__ void k_mlp(const float* __restrict__ g,
                      const float* __restrict__ lw1, const float* __restrict__ lb1,
                      const float* __restrict__ lw2, const float* __restrict__ lb2,
                      const float* __restrict__ lw3, const float* __restrict__ lb3,
                      float* __restrict__ out){
    __shared__ float t1[4][32];
    __shared__ float t2[4][32];
    int tid = threadIdx.x, sub = tid >> 5, j = tid & 31;
    int gi = blockIdx.x * 4 + sub;
    const float* gr = g + gi * 128;
    float s = lb1[j];
    for (int c = 0; c < 128; c++) s += gr[c] * lw1[c * 32 + j];
    t1[sub][j] = frelu(s);
    __syncthreads();
    float s2 = lb2[j];
    for (int k = 0; k < 32; k++) s2 += t1[sub][k] * lw2[k * 32 + j];
    t2[sub][j] = frelu(s2);
    __syncthreads();
    if (j == 0){
        float o = lb3[0];
        for (int k = 0; k < 32; k++) o += t2[sub][k] * lw3[k];
        out[gi] = frelu(o);
    }
}

extern "C" void kernel_launch(void* const* d_in, const int* in_sizes, int n_in,
                              void* d_out, int out_size, void* d_ws, size_t ws_size,
                              hipStream_t stream) {
    const float* x     = (const float*)d_in[0];
    const int*   ei    = (const int*)  d_in[1];
    const float* ef    = (const float*)d_in[2];
    const int*   batch = (const int*)  d_in[3];
    const float* W[3]   = {(const float*)d_in[4],  (const float*)d_in[10], (const float*)d_in[16]};
    const float* as_[3] = {(const float*)d_in[5],  (const float*)d_in[11], (const float*)d_in[17]};
    const float* ad_[3] = {(const float*)d_in[6],  (const float*)d_in[12], (const float*)d_in[18]};
    const float* We[3]  = {(const float*)d_in[7],  (const float*)d_in[13], (const float*)d_in[19]};
    const float* ae[3]  = {(const float*)d_in[8],  (const float*)d_in[14], (const float*)d_in[20]};
    const float* b_[3]  = {(const float*)d_in[9],  (const float*)d_in[15], (const float*)d_in[21]};
    const float* lw1 = (const float*)d_in[22]; const float* lb1 = (const float*)d_in[23];
    const float* lw2 = (const float*)d_in[24]; const float* lb2 = (const float*)d_in[25];
    const float* lw3 = (const float*)d_in[26]; const float* lb3 = (const float*)d_in[27];

    float* ws = (float*)d_ws;
    float* Bx   = ws;                      // layer out bf16 [NND*64 uints]
    float* Hbf  = Bx + 6400000;            // h bf16 [NND*64 uints]
    float* als  = Hbf + 6400000;           // [NND*4]
    float* ald  = als + 200000;            // [NND*4]
    float* g    = ald + 200000;            // [NG*128]
    float* partial = g + 262144;           // [MB*8]
    float* M    = partial + MB * 8;        // [96]
    float* sc   = M + 96;                  // [12] + pad
    int2*  se   = (int2*)(sc + 16);        // [NET] (src, eid)
    int*   pose = (int*)(se + NET);        // [NE]
    int*   rs   = pose + NE;               // [NND+1] (+pad)
    int*   cnt  = rs + NND + 4;            // [NND]
    int*   bsum = cnt + NND;               // [SCB]
    int*   boff = bsum + SCB;              // [SCB]

    unsigned short* Hb = (unsigned short*)Hbf;

    k_mean<<<MB, 256, 0, stream>>>((const float4*)ef, partial, g, cnt);
    k_prep<<<1, 128, 0, stream>>>(partial, We[0], ae[0], We[1], ae[1], We[2], ae[2], M, sc);

    k_hist<<<(NE + 255) / 256, 256, 0, stream>>>(ei, cnt, pose);
    k_scan1<<<SCB, 256, 0, stream>>>(cnt, bsum);
    k_scan2<<<1, 256, 0, stream>>>(bsum, boff, rs);
    k_scan3<<<SCB, 256, 0, stream>>>(cnt, boff, rs);
    k_scatter<<<(NET + 255) / 256, 256, 0, stream>>>(ei, rs, pose, se);

    const int GB = (NND + 63) / 64;        // 782
    for (int l = 0; l < 3; l++){
        if (l == 0)
            k_gemm<32, 30, 0><<<GB, 256, 0, stream>>>(x, W[l], as_[l], ad_[l],
                                                      Hb, als, ald);
        else
            k_gemm<128, 128, 1><<<GB, 256, 0, stream>>>(Bx, W[l], as_[l], ad_[l],
                                                        Hb, als, ald);
        k_gather<<<NND / 4, 256, 0, stream>>>(se, rs, (const float4*)ef,
                                              (const float4*)als, (const float4*)ald,
                                              M + l * 32, sc + l * 4,
                                              (const unsigned int*)Hb, b_[l],
                                              (unsigned int*)Bx);
    }

    k_pool<<<(NND + 31) / 32, 128, 0, stream>>>((const unsigned short*)Bx, batch, g);
    k_mlp<<<NG / 4, 128, 0, stream>>>(g, lw1, lb1, lw2, lb2, lw3, lb3, (float*)d_out);
}

// Round 12
// 459.820 us; speedup vs baseline: 1.7902x; 1.7902x over previous
//
#include <hip/hip_runtime.h>

#define NND 50000
#define NE  800000
#define NET 850000   // NE + NND self-loops
#define NG  2048
#define SCB 196      // scan blocks = ceil(NND/256)
#define MB  1024     // k_mean blocks

typedef __attribute__((ext_vector_type(8))) short short8;    // 8 bf16 (4 VGPRs)
typedef __attribute__((ext_vector_type(4))) float float4v;   // 4 fp32 acc

__device__ __forceinline__ float frelu(float v){ return v > 0.f ? v : 0.f; }

// round-to-nearest-even float -> bf16 bits
__device__ __forceinline__ unsigned short f2bf(float f){
    unsigned int u = __float_as_uint(f);
    u += 0x7FFFu + ((u >> 16) & 1u);
    return (unsigned short)(u >> 16);
}
__device__ __forceinline__ float bf2f(unsigned short s){
    return __uint_as_float(((unsigned int)s) << 16);
}

// ------- mean stage 1 + zero g/cnt: float4 grid-stride, block reduce ------------
__global__ __launch_bounds__(256) void k_mean(const float4* __restrict__ ef4,
                                              float* __restrict__ partial,
                                              float* __restrict__ gz,
                                              int* __restrict__ cntz){
    __shared__ float4 red[256];
    int t = threadIdx.x;
    int i0 = blockIdx.x * 256 + t;
    gz[i0] = 0.f;                            // MB*256 == NG*128 exactly
    if (i0 < NND) cntz[i0] = 0;
    const int S = MB * 256;
    float4 a = make_float4(0.f, 0.f, 0.f, 0.f);
    for (int j = i0; j < NE * 2; j += S){
        float4 v = ef4[j];
        a.x += v.x; a.y += v.y; a.z += v.z; a.w += v.w;
    }
    red[t] = a;
    __syncthreads();
    for (int off = 128; off >= 2; off >>= 1){    // even offsets preserve parity
        if (t < off){
            float4 o = red[t + off];
            float4 m = red[t];
            m.x += o.x; m.y += o.y; m.z += o.z; m.w += o.w;
            red[t] = m;
        }
        __syncthreads();
    }
    if (t < 8){
        float v = (t < 4) ? ((const float*)&red[0])[t]
                          : ((const float*)&red[1])[t - 4];
        partial[blockIdx.x * 8 + t] = v;
    }
}

// -------- prep: reduce partials -> mean; M[3][8][4]; self-loop consts sc[3][4] --
__global__ void k_prep(const float* __restrict__ partial,
                       const float* __restrict__ We1, const float* __restrict__ ae1,
                       const float* __restrict__ We2, const float* __restrict__ ae2,
                       const float* __restrict__ We3, const float* __restrict__ ae3,
                       float* __restrict__ M, float* __restrict__ sc){
    __shared__ float me[8];
    __shared__ float pm[16][8];
    __shared__ float Ms[96];
    int t = threadIdx.x;
    {
        int ch = t & 7, seg = t >> 3;
        float s = 0.f;
        for (int j = seg; j < MB; j += 16) s += partial[j * 8 + ch];
        pm[seg][ch] = s;
    }
    __syncthreads();
    if (t < 8){
        float s = 0.f;
        for (int i = 0; i < 16; i++) s += pm[i][t];
        me[t] = s * (1.0f / NE);
    }
    if (t < 96){
        int l = t >> 5, f = (t >> 2) & 7, h = t & 3;
        const float* We = (l == 0) ? We1 : ((l == 1) ? We2 : We3);
        const float* ae = (l == 0) ? ae1 : ((l == 1) ? ae2 : ae3);
        float s = 0.f;
        for (int c = 0; c < 32; c++) s += We[f * 128 + h * 32 + c] * ae[h * 32 + c];
        M[t] = s; Ms[t] = s;
    }
    __syncthreads();
    if (t < 12){
        int l = t >> 2, h = t & 3;
        float s = 0.f;
        for (int f = 0; f < 8; f++) s += me[f] * Ms[l * 32 + f * 4 + h];
        sc[t] = s;
    }
}

// ------------- MFMA GEMM: h = x @ W (bf16), fused als/ald epilogue --------------
// 64 rows x 128 cols per 256-thread block. BFIN: x is packed bf16 rows.
template<int FIN, int FINR, int BFIN>
__global__ __launch_bounds__(256) void k_gemm(
        const void* __restrict__ xv, const float* __restrict__ W,
        const float* __restrict__ asrc, const float* __restrict__ adst,
        unsigned short* __restrict__ h, float* __restrict__ als,
        float* __restrict__ ald){
    constexpr int KS = FIN + 8;
    constexpr int SZ1 = 64 * KS + 128 * KS;
    constexpr int SZ2 = 64 * 136;
    constexpr int LSZ = SZ1 > SZ2 ? SZ1 : SZ2;
    __shared__ unsigned short lds[LSZ];
    unsigned short* xa = lds;                // [64][KS]
    unsigned short* wb = lds + 64 * KS;      // [128][KS]
    int t = threadIdx.x;
    int r0 = blockIdx.x * 64;

    if (BFIN){
        const unsigned int* xu = (const unsigned int*)xv;
        for (int i = t; i < 64 * (FIN / 2); i += 256){
            int r = i / (FIN / 2), kp = i % (FIN / 2);
            int gr = r0 + r;
            unsigned int pk = (gr < NND) ? xu[gr * (FINR / 2) + kp] : 0u;
            *(unsigned int*)&xa[r * KS + 2 * kp] = pk;
        }
    } else {
        const float* x = (const float*)xv;
        for (int i = t; i < 64 * (FIN / 2); i += 256){
            int r = i / (FIN / 2), kp = i % (FIN / 2);
            int gr = r0 + r, k = 2 * kp;
            float v0 = 0.f, v1 = 0.f;
            if (gr < NND){
                if (k     < FINR) v0 = x[gr * FINR + k];
                if (k + 1 < FINR) v1 = x[gr * FINR + k + 1];
            }
            unsigned int pk = (unsigned int)f2bf(v0) | ((unsigned int)f2bf(v1) << 16);
            *(unsigned int*)&xa[r * KS + k] = pk;
        }
    }
    for (int i = t; i < 128 * (FIN / 2); i += 256){
        int n = i & 127, kp = i >> 7, k = 2 * kp;
        float v0 = (k     < FINR) ? W[k * 128 + n]       : 0.f;
        float v1 = (k + 1 < FINR) ? W[(k + 1) * 128 + n] : 0.f;
        unsigned int pk = (unsigned int)f2bf(v0) | ((unsigned int)f2bf(v1) << 16);
        *(unsigned int*)&wb[n * KS + k] = pk;
    }
    __syncthreads();

    int wv = t >> 6, lane = t & 63;
    int quad = lane >> 4, lrow = lane & 15;
    int arow = wv * 16 + lrow;
    int koff = quad * 8;
    float4v acc[8];
    #pragma unroll
    for (int nt = 0; nt < 8; nt++) acc[nt] = (float4v){0.f, 0.f, 0.f, 0.f};
    #pragma unroll
    for (int ks = 0; ks < FIN / 32; ks++){
        short8 af = *(const short8*)&xa[arow * KS + ks * 32 + koff];
        #pragma unroll
        for (int nt = 0; nt < 8; nt++){
            short8 bf = *(const short8*)&wb[(nt * 16 + lrow) * KS + ks * 32 + koff];
            acc[nt] = __builtin_amdgcn_mfma_f32_16x16x32_bf16(af, bf, acc[nt], 0, 0, 0);
        }
    }
    __syncthreads();
    unsigned short* hb = lds;                // [64][136]
    #pragma unroll
    for (int nt = 0; nt < 8; nt++){
        #pragma unroll
        for (int reg = 0; reg < 4; reg++){
            int lr = wv * 16 + quad * 4 + reg;
            hb[lr * 136 + nt * 16 + lrow] = f2bf(acc[nt][reg]);
        }
    }
    __syncthreads();
    {
        int r = t >> 2, hd = t & 3;
        int gr = r0 + r;
        float sa = 0.f, sd = 0.f;
        const unsigned short* hp = &hb[r * 136 + hd * 32];
        #pragma unroll
        for (int c = 0; c < 32; c++){
            float hv = bf2f(hp[c]);
            sa += hv * asrc[hd * 32 + c];
            sd += hv * adst[hd * 32 + c];
        }
        if (gr < NND){ als[gr * 4 + hd] = sa; ald[gr * 4 + hd] = sd; }
    }
    for (int i = t; i < 64 * 16; i += 256){
        int r = i >> 4, c8 = i & 15;
        int gr = r0 + r;
        if (gr < NND)
            *(int4*)&h[gr * 128 + c8 * 8] = *(const int4*)&hb[r * 136 + c8 * 8];
    }
}

// ------- CSR build: histogram of dst (real edges) + position assignment --------
__global__ void k_hist(const int* __restrict__ ei, int* __restrict__ cnt,
                       int* __restrict__ pose){
    int e = blockIdx.x * 256 + threadIdx.x;
    if (e >= NE) return;
    int d = ei[NE + e];
    pose[e] = atomicAdd(&cnt[d], 1);
}

// ---------------- scan phase 1: per-block sums of (cnt+1) -----------------------
__global__ __launch_bounds__(256) void k_scan1(const int* __restrict__ cnt,
                                               int* __restrict__ bsum){
    __shared__ int red[256];
    int t = threadIdx.x;
    int idx = blockIdx.x * 256 + t;
    red[t] = (idx < NND) ? (cnt[idx] + 1) : 0;
    __syncthreads();
    for (int off = 128; off > 0; off >>= 1){
        if (t < off) red[t] += red[t + off];
        __syncthreads();
    }
    if (t == 0) bsum[blockIdx.x] = red[0];
}

// ---------------- scan phase 2: scan the 196 block sums -------------------------
__global__ __launch_bounds__(256) void k_scan2(const int* __restrict__ bsum,
                                               int* __restrict__ boff,
                                               int* __restrict__ rs){
    __shared__ int ls[256];
    int t = threadIdx.x;
    int v = (t < SCB) ? bsum[t] : 0;
    ls[t] = v;
    __syncthreads();
    for (int off = 1; off < 256; off <<= 1){
        int u = (t >= off) ? ls[t - off] : 0;
        __syncthreads();
        ls[t] += u;
        __syncthreads();
    }
    if (t < SCB) boff[t] = ls[t] - bsum[t];
    if (t == 0)  rs[NND] = ls[255];
}

// ---------------- scan phase 3: per-block exclusive scan + offset ---------------
__global__ __launch_bounds__(256) void k_scan3(const int* __restrict__ cnt,
                                               const int* __restrict__ boff,
                                               int* __restrict__ rs){
    __shared__ int ls[256];
    int t = threadIdx.x;
    int idx = blockIdx.x * 256 + t;
    int v = (idx < NND) ? (cnt[idx] + 1) : 0;
    ls[t] = v;
    __syncthreads();
    for (int off = 1; off < 256; off <<= 1){
        int u = (t >= off) ? ls[t - off] : 0;
        __syncthreads();
        ls[t] += u;
        __syncthreads();
    }
    if (idx < NND) rs[idx] = boff[blockIdx.x] + ls[t] - v;
}

// ---------------- CSR build: scatter — NO atomics (pose precomputed) ------------
__global__ void k_scatter(const int* __restrict__ ei, const int* __restrict__ rs,
                          const int* __restrict__ pose, int* __restrict__ srcarr,
                          int* __restrict__ slotof){
    int e = blockIdx.x * 256 + threadIdx.x;
    if (e >= NET) return;
    if (e < NE){
        int s = ei[e], d = ei[NE + e];
        int slot = rs[d] + 1 + pose[e];
        srcarr[slot] = s;
        slotof[e] = slot;
    } else {
        int n = e - NE;
        srcarr[rs[n]] = n;
    }
}

// ---------------- per-edge attention weights -> CSR slot order ------------------
__global__ __launch_bounds__(256) void k_weight(
        const int* __restrict__ ei, const float* __restrict__ ef,
        const float4* __restrict__ als4, const float4* __restrict__ ald4,
        const float* __restrict__ Mg, const float* __restrict__ sc4g,
        const int* __restrict__ rs, const int* __restrict__ slotof,
        float4* __restrict__ wS){
    __shared__ float Ms[32];
    __shared__ float Scs[4];
    int t = threadIdx.x;
    if (t < 32) Ms[t] = Mg[t];
    if (t < 4)  Scs[t] = sc4g[t];
    __syncthreads();
    int e = blockIdx.x * 256 + t;
    if (e < NE){
        int s = ei[e], d = ei[NE + e];
        const float4* efp = (const float4*)ef;
        float4 u = efp[e * 2], v = efp[e * 2 + 1];
        float4 A = als4[s], D = ald4[d];
        float4 w;
        float* wp = &w.x;
        const float* Ap = &A.x; const float* Dp = &D.x;
        #pragma unroll
        for (int h = 0; h < 4; h++){
            float ae = u.x * Ms[0 + h]  + u.y * Ms[4 + h]
                     + u.z * Ms[8 + h]  + u.w * Ms[12 + h]
                     + v.x * Ms[16 + h] + v.y * Ms[20 + h]
                     + v.z * Ms[24 + h] + v.w * Ms[28 + h];
            float a = Ap[h] + Dp[h] + ae;
            a = a > 0.f ? a : 0.2f * a;
            wp[h] = __expf(a);
        }
        wS[slotof[e]] = w;
    } else if (e < NE + NND){
        int n = e - NE;
        float4 A = als4[n], D = ald4[n];
        float4 w;
        float* wp = &w.x;
        const float* Ap = &A.x; const float* Dp = &D.x;
        #pragma unroll
        for (int h = 0; h < 4; h++){
            float a = Ap[h] + Dp[h] + Scs[h];
            a = a > 0.f ? a : 0.2f * a;
            wp[h] = __expf(a);
        }
        wS[rs[n]] = w;
    }
}

// ---------------- gather: bf16 h rows, one wave/node, 8-deep pipeline -----------
__global__ __launch_bounds__(256) void k_gather(
        const int* __restrict__ srcarr, const int* __restrict__ rs,
        const float* __restrict__ wS,
        const unsigned int* __restrict__ HU,    // bf16x2 rows [NND][64]
        const float* __restrict__ b, unsigned int* __restrict__ outU){
    int wid  = threadIdx.x >> 6;
    int lane = threadIdx.x & 63;
    int n = blockIdx.x * 4 + wid;
    int start = rs[n], end = rs[n + 1];
    int cnt = end - start;
    int mh = lane >> 4;
    float ax = 0.f, ay = 0.f, accw = 0.f;

    int s[8]; float w[8];
    int k = 0;
    if (cnt >= 8){
        #pragma unroll
        for (int j = 0; j < 8; j++){
            int i = start + j;
            s[j] = srcarr[i];
            w[j] = wS[i * 4 + mh];
        }
    }
    while (k + 8 <= cnt){
        int cs[8]; float cw[8];
        #pragma unroll
        for (int j = 0; j < 8; j++){ cs[j] = s[j]; cw[j] = w[j]; }
        k += 8;
        if (k + 8 <= cnt){
            #pragma unroll
            for (int j = 0; j < 8; j++){
                int i = start + k + j;
                s[j] = srcarr[i];
                w[j] = wS[i * 4 + mh];
            }
        }
        unsigned int hv[8];
        #pragma unroll
        for (int j = 0; j < 8; j++) hv[j] = HU[cs[j] * 64 + lane];
        #pragma unroll
        for (int j = 0; j < 8; j++){
            float lo = __uint_as_float(hv[j] << 16);
            float hi = __uint_as_float(hv[j] & 0xFFFF0000u);
            ax += cw[j] * lo;
            ay += cw[j] * hi;
            accw += cw[j];
        }
    }
    int rem = cnt - k;
    if (rem > 0){
        int ts[8]; float tw[8];
        #pragma unroll
        for (int j = 0; j < 8; j++){
            bool v = j < rem;
            int i = v ? (start + k + j) : start;
            ts[j] = srcarr[i];
            tw[j] = v ? wS[i * 4 + mh] : 0.f;
        }
        unsigned int hv[8];
        #pragma unroll
        for (int j = 0; j < 8; j++) hv[j] = HU[ts[j] * 64 + lane];
        #pragma unroll
        for (int j = 0; j < 8; j++){
            float lo = __uint_as_float(hv[j] << 16);
            float hi = __uint_as_float(hv[j] & 0xFFFF0000u);
            ax += tw[j] * lo;
            ay += tw[j] * hi;
            accw += tw[j];
        }
    }
    float inv = 1.f / (accw + 1e-16f);
    int c0 = 2 * lane;
    float ox = frelu(ax * inv + b[c0]);
    float oy = frelu(ay * inv + b[c0 + 1]);
    outU[n * 64 + lane] = (unsigned int)f2bf(ox) | ((unsigned int)f2bf(oy) << 16);
}

// ------- global add pool (bf16 in): run-length compress sorted batch ------------
__global__ __launch_bounds__(128) void k_pool(const unsigned short* __restrict__ y,
                                              const int* __restrict__ batch,
                                              float* __restrict__ g){
    int c = threadIdx.x;
    int n0 = blockIdx.x * 32;
    if (n0 >= NND) return;
    int cur = batch[n0];
    float s = 0.f;
    for (int k = 0; k < 32; k++){
        int n = n0 + k;
        if (n >= NND) break;
        int bg = batch[n];
        if (bg != cur){
            atomicAdd(&g[cur * 128 + c], s);
            s = 0.f; cur = bg;
        }
        s += bf2f(y[n * 128 + c]);
    }
    atomicAdd(&g[cur * 128 + c], s);
}

// ---------------- MLP head: 128->32->32->1 --------------------------------------
__global__ void k_mlp(const float* __restrict__ g,
                      const float* __restrict__ lw1, const float* __restrict__ lb1,
                      const float* __restrict__ lw2, const float* __restrict__ lb2,
                      const float* __restrict__ lw3, const float* __restrict__ lb3,
                      float* __restrict__ out){
    __shared__ float t1[4][32];
    __shared__ float t2[4][32];
    int tid = threadIdx.x, sub = tid >> 5, j = tid & 31;
    int gi = blockIdx.x * 4 + sub;
    const float* gr = g + gi * 128;
    float s = lb1[j];
    for (int c = 0; c < 128; c++) s += gr[c] * lw1[c * 32 + j];
    t1[sub][j] = frelu(s);
    __syncthreads();
    float s2 = lb2[j];
    for (int k = 0; k < 32; k++) s2 += t1[sub][k] * lw2[k * 32 + j];
    t2[sub][j] = frelu(s2);
    __syncthreads();
    if (j == 0){
        float o = lb3[0];
        for (int k = 0; k < 32; k++) o += t2[sub][k] * lw3[k];
        out[gi] = frelu(o);
    }
}

extern "C" void kernel_launch(void* const* d_in, const int* in_sizes, int n_in,
                              void* d_out, int out_size, void* d_ws, size_t ws_size,
                              hipStream_t stream) {
    const float* x     = (const float*)d_in[0];
    const int*   ei    = (const int*)  d_in[1];
    const float* ef    = (const float*)d_in[2];
    const int*   batch = (const int*)  d_in[3];
    const float* W[3]   = {(const float*)d_in[4],  (const float*)d_in[10], (const float*)d_in[16]};
    const float* as_[3] = {(const float*)d_in[5],  (const float*)d_in[11], (const float*)d_in[17]};
    const float* ad_[3] = {(const float*)d_in[6],  (const float*)d_in[12], (const float*)d_in[18]};
    const float* We[3]  = {(const float*)d_in[7],  (const float*)d_in[13], (const float*)d_in[19]};
    const float* ae[3]  = {(const float*)d_in[8],  (const float*)d_in[14], (const float*)d_in[20]};
    const float* b_[3]  = {(const float*)d_in[9],  (const float*)d_in[15], (const float*)d_in[21]};
    const float* lw1 = (const float*)d_in[22]; const float* lb1 = (const float*)d_in[23];
    const float* lw2 = (const float*)d_in[24]; const float* lb2 = (const float*)d_in[25];
    const float* lw3 = (const float*)d_in[26]; const float* lb3 = (const float*)d_in[27];

    float* ws = (float*)d_ws;
    float* Bx   = ws;                      // layer out bf16 [NND*64 uints]
    float* Hbf  = Bx + 3200000;            // h bf16 [NND*64 uints]
    float* wSf  = Hbf + 3200000;           // weights/slot  [NET*4]
    float* als  = wSf + 3400000;           // [NND*4]
    float* ald  = als + 200000;            // [NND*4]
    float* g    = ald + 200000;            // [NG*128]
    float* partial = g + 262144;           // [MB*8]
    float* M    = partial + MB * 8;        // [96]
    float* sc   = M + 96;                  // [12] + pad
    int*   srcarr = (int*)(sc + 16);       // [NET]
    int*   slotof = srcarr + NET;          // [NE]
    int*   pose   = slotof + NE;           // [NE]
    int*   rs     = pose + NE;             // [NND+1] (+pad)
    int*   cnt    = rs + NND + 4;          // [NND]
    int*   bsum   = cnt + NND;             // [SCB]
    int*   boff   = bsum + SCB;            // [SCB]

    unsigned short* Hb = (unsigned short*)Hbf;

    k_mean<<<MB, 256, 0, stream>>>((const float4*)ef, partial, g, cnt);
    k_prep<<<1, 128, 0, stream>>>(partial, We[0], ae[0], We[1], ae[1], We[2], ae[2], M, sc);

    k_hist<<<(NE + 255) / 256, 256, 0, stream>>>(ei, cnt, pose);
    k_scan1<<<SCB, 256, 0, stream>>>(cnt, bsum);
    k_scan2<<<1, 256, 0, stream>>>(bsum, boff, rs);
    k_scan3<<<SCB, 256, 0, stream>>>(cnt, boff, rs);
    k_scatter<<<(NET + 255) / 256, 256, 0, stream>>>(ei, rs, pose, srcarr, slotof);

    const int GB = (NND + 63) / 64;        // 782
    for (int l = 0; l < 3; l++){
        if (l == 0)
            k_gemm<32, 30, 0><<<GB, 256, 0, stream>>>(x, W[l], as_[l], ad_[l],
                                                      Hb, als, ald);
        else
            k_gemm<128, 128, 1><<<GB, 256, 0, stream>>>(Bx, W[l], as_[l], ad_[l],
                                                        Hb, als, ald);
        k_weight<<<(NE + NND + 255) / 256, 256, 0, stream>>>(
            ei, ef, (const float4*)als, (const float4*)ald,
            M + l * 32, sc + l * 4, rs, slotof, (float4*)wSf);
        k_gather<<<NND / 4, 256, 0, stream>>>(srcarr, rs, wSf,
                                              (const unsigned int*)Hb, b_[l],
                                              (unsigned int*)Bx);
    }

    k_pool<<<(NND + 31) / 32, 128, 0, stream>>>((const unsigned short*)Bx, batch, g);
    k_mlp<<<NG / 4, 128, 0, stream>>>(g, lw1, lb1, lw2, lb2, lw3, lb3, (float*)d_out);
}